// Round 2
// baseline (543.506 us; speedup 1.0000x reference)
//
#include <hip/hip_runtime.h>

typedef short s8v __attribute__((ext_vector_type(8)));
typedef float f4v __attribute__((ext_vector_type(4)));

static constexpr int Bc = 32, Tq = 256, Tkc = 1024, Dc = 512, Hc = 4;
static constexpr float BN_EPS = 1e-5f;

__device__ inline ushort f2bf(float x) {
    union { float f; unsigned int u; } v; v.f = x;
    unsigned int r = v.u + 0x7fff + ((v.u >> 16) & 1);   // RNE
    return (ushort)(r >> 16);
}

// ---------------------------------------------------------------------------
// Fold eval-mode BN into the following linear layer; weights out in bf16.
// ---------------------------------------------------------------------------
__global__ __launch_bounds__(256) void fold_bn(
    const float* __restrict__ W, const float* __restrict__ gamma,
    const float* __restrict__ beta, const float* __restrict__ mean,
    const float* __restrict__ var, ushort* __restrict__ Wp,
    float* __restrict__ bias, int K)
{
    int n = blockIdx.x;
    int tid = threadIdx.x;
    float acc = 0.f;
    for (int k = tid; k < K; k += 256) {
        float sc = gamma[k] * rsqrtf(var[k] + BN_EPS);
        float sh = beta[k] - mean[k] * sc;
        float w = W[(long)n * K + k];
        Wp[(long)n * K + k] = f2bf(w * sc);
        acc = fmaf(w, sh, acc);
    }
    __shared__ float red[256];
    red[tid] = acc;
    __syncthreads();
    for (int s = 128; s > 0; s >>= 1) {
        if (tid < s) red[tid] += red[tid + s];
        __syncthreads();
    }
    if (tid == 0) bias[n] = red[0];
}

// ---------------------------------------------------------------------------
__global__ __launch_bounds__(256) void f32_to_bf16(
    const float* __restrict__ x, ushort* __restrict__ y)
{
    long i = ((long)blockIdx.x * 256 + threadIdx.x) * 4;
    float4 v = *(const float4*)&x[i];
    ushort4 o = { f2bf(v.x), f2bf(v.y), f2bf(v.z), f2bf(v.w) };
    *(ushort4*)&y[i] = o;
}

// ---------------------------------------------------------------------------
// Fused: h_bf[b][k][d] = bf16(h[b][k][d]) AND hT[b][d][k] = bf16(h[b][k][d])
// ---------------------------------------------------------------------------
__global__ __launch_bounds__(256) void conv_h(
    const float* __restrict__ h, ushort* __restrict__ h_bf,
    ushort* __restrict__ hT)
{
    __shared__ float tl[64][65];
    int b = blockIdx.z, k0 = blockIdx.y * 64, d0 = blockIdx.x * 64;
    int t = threadIdx.x, r = t >> 4, c = (t & 15) * 4;
    const float* hb = h + ((long)b * Tkc + k0) * Dc + d0;
    ushort* sb = h_bf + ((long)b * Tkc + k0) * Dc + d0;
    #pragma unroll
    for (int i = 0; i < 4; i++) {
        int rr = r + i * 16;
        float4 v = *(const float4*)&hb[(long)rr * Dc + c];
        tl[rr][c + 0] = v.x; tl[rr][c + 1] = v.y;
        tl[rr][c + 2] = v.z; tl[rr][c + 3] = v.w;
        ushort4 sv = { f2bf(v.x), f2bf(v.y), f2bf(v.z), f2bf(v.w) };
        *(ushort4*)&sb[(long)rr * Dc + c] = sv;
    }
    __syncthreads();
    ushort* o = hT + ((long)b * Dc + d0) * Tkc + k0;
    #pragma unroll
    for (int i = 0; i < 4; i++) {
        int dr = r + i * 16;
        ushort4 ov = { f2bf(tl[c + 0][dr]), f2bf(tl[c + 1][dr]),
                       f2bf(tl[c + 2][dr]), f2bf(tl[c + 3][dr]) };
        *(ushort4*)&o[(long)dr * Tkc + c] = ov;
    }
}

// ---------------------------------------------------------------------------
// out_c[m][n] = bias[n]  (split-K atomic accumulation target)
// ---------------------------------------------------------------------------
__global__ __launch_bounds__(256) void init_c(
    float* __restrict__ C, const float* __restrict__ bias)
{
    long i = (long)blockIdx.x * 256 + threadIdx.x;   // float4 index
    int n4 = (int)(i & 127);
    float4 b = ((const float4*)bias)[n4];
    ((float4*)C)[i] = b;
}

// ---------------------------------------------------------------------------
// 256x256-tile bf16 MFMA GEMM (NT), BK=64, 8 waves (2M x 4N), 512 threads.
// 8-phase schedule, 2 K-tiles/iteration, double-buffered 128KiB LDS.
//
// Region lifetimes (reads span BOTH LDS halves each phase, since wave w
// reads its own 128-row A-half / 64-row B-quarter):
//   buf0.B read P1+P2; buf0.A read P1+P3; buf1.B read P5+P6; buf1.A read P5+P7.
// Stage placement (each strictly after its region's last-reader barrier):
//   P1: t0+1.Bhi->buf1   P2: t0+1.Ahi->buf1
//   P3: t0+2.Blo->buf0   P4: t0+2.Alo->buf0 + WAITV(4)  [t0+1 all landed]
//   P5: t0+2.Bhi->buf0   P6: t0+2.Ahi->buf0
//   P7: t0+3.Blo->buf1   P8: t0+3.Alo->buf1 + WAITV(4)  [t0+2 all landed]
// vmcnt is per-wave but each wave waits for its own stages then barriers,
// so after the barrier all waves' stages have landed (m201 pattern).
// Tail iteration: keep P1/P2 stages (they complete the last tile),
// WAITV(0) at P4, nothing after.
// ---------------------------------------------------------------------------
typedef __attribute__((address_space(1))) void gvoid;
typedef __attribute__((address_space(3))) void lvoid;

#define GLOAD(gp, lp) __builtin_amdgcn_global_load_lds((gvoid*)(gp), (lvoid*)(lp), 16, 0, 0)
#define BAR() asm volatile("s_barrier" ::: "memory")
#define WAITV(n) asm volatile("s_waitcnt vmcnt(" #n ")" ::: "memory")

#define STG_A(t, h, bufb) do { \
    GLOAD(sA + (long)((h) * 128) * lda + (t) * 64, &lds[(bufb) + (h) * 8192 + ldsAc]); \
    GLOAD(sA + (long)((h) * 128 + 8) * lda + (t) * 64, &lds[(bufb) + (h) * 8192 + ldsAc + 512]); \
} while (0)
#define STG_B(t, h, bufb) do { \
    GLOAD(sB + (long)((h) * 128) * ldb + (t) * 64, &lds[(bufb) + 16384 + (h) * 8192 + ldsBc]); \
    GLOAD(sB + (long)((h) * 128 + 8) * ldb + (t) * 64, &lds[(bufb) + 16384 + (h) * 8192 + ldsBc + 512]); \
} while (0)

// read 4 A-frags (quarter mh_ of the wave's 128-row half) x 2 k-steps
#define RD_A(mh_, bufb) do { \
    _Pragma("unroll") \
    for (int mi = 0; mi < 4; mi++) { \
        aF[mi][0] = *(const s8v*)&lds[(bufb) + ahalf + ((mh_) * 4 + mi) * 1024 + aoff]; \
        aF[mi][1] = *(const s8v*)&lds[(bufb) + ahalf + ((mh_) * 4 + mi) * 1024 + (aoff ^ 32)]; \
    } \
} while (0)
// read 2 B-frags (pair nh_ of the wave's 64-row quarter) x 2 k-steps
#define RD_B(dst, nh_, bufb) do { \
    _Pragma("unroll") \
    for (int ni = 0; ni < 2; ni++) { \
        dst[ni][0] = *(const s8v*)&lds[(bufb) + bhalf + ((nh_) * 2 + ni) * 1024 + aoff]; \
        dst[ni][1] = *(const s8v*)&lds[(bufb) + bhalf + ((nh_) * 2 + ni) * 1024 + (aoff ^ 32)]; \
    } \
} while (0)
// one quadrant: 4m x 2n x 2k = 16 MFMA
#define MFQ(mh_, nh_, bv) do { \
    __builtin_amdgcn_s_setprio(1); \
    _Pragma("unroll") \
    for (int mi = 0; mi < 4; mi++) \
        _Pragma("unroll") \
        for (int ni = 0; ni < 2; ni++) { \
            acc[(mh_) * 4 + mi][(nh_) * 2 + ni] = __builtin_amdgcn_mfma_f32_16x16x32_bf16( \
                aF[mi][0], bv[ni][0], acc[(mh_) * 4 + mi][(nh_) * 2 + ni], 0, 0, 0); \
            acc[(mh_) * 4 + mi][(nh_) * 2 + ni] = __builtin_amdgcn_mfma_f32_16x16x32_bf16( \
                aF[mi][1], bv[ni][1], acc[(mh_) * 4 + mi][(nh_) * 2 + ni], 0, 0, 0); \
        } \
    __builtin_amdgcn_s_setprio(0); \
} while (0)

#define ITER(T0, PF) do { \
    const int t0_ = (T0); \
    /* P1: rd t0 A-q0, B-q0 | stage t0+1.Bhi -> buf1 */ \
    RD_A(0, 0); RD_B(bLo, 0, 0); \
    STG_B(t0_ + 1, 1, 32768); \
    BAR(); MFQ(0, 0, bLo); BAR(); \
    /* P2: rd t0 B-q1 | stage t0+1.Ahi -> buf1 */ \
    RD_B(bHi, 1, 0); \
    STG_A(t0_ + 1, 1, 32768); \
    BAR(); MFQ(0, 1, bHi); BAR(); \
    /* P3: rd t0 A-q1 | stage t0+2.Blo -> buf0 */ \
    RD_A(1, 0); \
    if (PF) STG_B(t0_ + 2, 0, 0); \
    BAR(); MFQ(1, 0, bLo); BAR(); \
    /* P4: stage t0+2.Alo -> buf0 | drain tile t0+1 (8 oldest) */ \
    if (PF) { STG_A(t0_ + 2, 0, 0); WAITV(4); } else { WAITV(0); } \
    BAR(); MFQ(1, 1, bHi); BAR(); \
    /* P5: rd t0+1 A-q0, B-q0 | stage t0+2.Bhi -> buf0 */ \
    RD_A(0, 32768); RD_B(bLo, 0, 32768); \
    if (PF) STG_B(t0_ + 2, 1, 0); \
    BAR(); MFQ(0, 0, bLo); BAR(); \
    /* P6: rd t0+1 B-q1 | stage t0+2.Ahi -> buf0 */ \
    RD_B(bHi, 1, 32768); \
    if (PF) STG_A(t0_ + 2, 1, 0); \
    BAR(); MFQ(0, 1, bHi); BAR(); \
    /* P7: rd t0+1 A-q1 | stage t0+3.Blo -> buf1 */ \
    RD_A(1, 32768); \
    if (PF) STG_B(t0_ + 3, 0, 32768); \
    BAR(); MFQ(1, 0, bLo); BAR(); \
    /* P8: stage t0+3.Alo -> buf1 | drain tile t0+2 (8 oldest) */ \
    if (PF) { STG_A(t0_ + 3, 0, 32768); WAITV(4); } \
    BAR(); MFQ(1, 1, bHi); BAR(); \
} while (0)

__global__ __launch_bounds__(512, 2) void gemm256(
    const ushort* __restrict__ A, const ushort* __restrict__ B,
    float* __restrict__ Cf, ushort* __restrict__ Cb,
    const float* __restrict__ bias, int atom,
    int K, int lda, int ldb, int ldc,
    long sAh, long sAb, long sBh, long sBb, long sCh, long sCb,
    int nB, int nxs, int zbits)
{
    __shared__ ushort lds[65536];   // 128 KiB: buf{0,1} x (A 32KB + B 32KB)

    int bx = blockIdx.x;
    int z = bx & ((1 << zbits) - 1);
    int j2 = bx >> zbits;
    int gx = j2 & ((1 << nxs) - 1);
    int gy = j2 >> nxs;
    int hh = z / nB, bb = z - hh * nB;
    A += hh * sAh + bb * sAb;
    B += hh * sBh + bb * sBb;
    long coff = hh * sCh + bb * sCb;

    int tid = threadIdx.x;
    int w = tid >> 6, l = tid & 63;
    int m0 = gy << 8, n0 = gx << 8;

    // staging: wave w stages rows w*16..+15 of each 128-row half; lane l
    // stages row w*16+(l>>3), source k-chunk (l&7)^((l>>3)&7) [swizzle on
    // the global SOURCE; LDS dest stays linear, rule 21]
    int skc = ((l & 7) ^ ((l >> 3) & 7)) * 8;
    const ushort* sA = A + (long)(m0 + w * 16 + (l >> 3)) * lda + skc;
    const ushort* sB = B + (long)(n0 + w * 16 + (l >> 3)) * ldb + skc;
    int ldsAc = w * 1024;              // dest chunk base (ushorts); 2nd gload +512
    int ldsBc = w * 1024;

    // fragment reads: LDS slot c of row r holds global k-chunk c^(r&7);
    // lane wants chunk kc16 (k-step 0) / kc16+4 (k-step 1, = aoff^32)
    int fr = l & 15, kc16 = l >> 4;
    int ahalf = (w >> 2) * 8192;
    int bhalf = 16384 + ((w & 3) >> 1) * 8192 + (w & 1) * 4096;
    int aoff = fr * 64 + ((kc16 ^ (fr & 7)) << 3);

    s8v aF[4][2], bLo[2][2], bHi[2][2];
    f4v acc[8][4] = {};

    // prologue: tile0 full -> buf0 (8 gloads), tile1 {Blo,Alo} -> buf1 (4);
    // WAITV(4) drains buf0's 8, leaves tile1's 4 in flight.
    STG_A(0, 0, 0); STG_A(0, 1, 0); STG_B(0, 0, 0); STG_B(0, 1, 0);
    STG_B(1, 0, 32768); STG_A(1, 0, 32768);
    WAITV(4);
    BAR();

    int NI = K >> 7;                   // iterations of 2 K-tiles (BK=64)
    for (int i = 0; i < NI - 1; i++) { ITER(2 * i, 1); }
    ITER(2 * (NI - 1), 0);

    // epilogue: C row = (l>>4)*4 + r, col = l&15
    int wm = (w >> 2) * 128, wn = (w & 3) * 64;
    #pragma unroll
    for (int mi = 0; mi < 8; mi++) {
        #pragma unroll
        for (int ni = 0; ni < 4; ni++) {
            int n = n0 + wn + ni * 16 + fr;
            float bv = bias ? bias[n] : 0.f;
            #pragma unroll
            for (int r = 0; r < 4; r++) {
                int m = m0 + wm + mi * 16 + kc16 * 4 + r;
                float v = acc[mi][ni][r] + bv;
                long off = coff + (long)m * ldc + n;
                if (atom)    atomicAdd(&Cf[off], v);
                else if (Cb) Cb[off] = f2bf(v);
                else         Cf[off] = v;
            }
        }
    }
}

// ---------------------------------------------------------------------------
// In-place row softmax (rows of 1024 f32) + bf16 copy.
// ---------------------------------------------------------------------------
__global__ __launch_bounds__(256) void softmax_rows(
    float* __restrict__ E, ushort* __restrict__ Abf)
{
    int wave = threadIdx.x >> 6;
    int lane = threadIdx.x & 63;
    long row = (long)blockIdx.x * 4 + wave;
    float4* rp = (float4*)(E + row * 1024);
    ushort* op = Abf + row * 1024;

    float4 v[4];
    float mx = -3.4e38f;
    #pragma unroll
    for (int i = 0; i < 4; i++) {
        v[i] = rp[lane + (i << 6)];
        mx = fmaxf(mx, fmaxf(fmaxf(v[i].x, v[i].y), fmaxf(v[i].z, v[i].w)));
    }
    #pragma unroll
    for (int o = 32; o > 0; o >>= 1) mx = fmaxf(mx, __shfl_xor(mx, o, 64));

    float sum = 0.f;
    #pragma unroll
    for (int i = 0; i < 4; i++) {
        v[i].x = __expf(v[i].x - mx);
        v[i].y = __expf(v[i].y - mx);
        v[i].z = __expf(v[i].z - mx);
        v[i].w = __expf(v[i].w - mx);
        sum += v[i].x + v[i].y + v[i].z + v[i].w;
    }
    #pragma unroll
    for (int o = 32; o > 0; o >>= 1) sum += __shfl_xor(sum, o, 64);

    float inv = 1.f / sum;
    #pragma unroll
    for (int i = 0; i < 4; i++) {
        v[i].x *= inv; v[i].y *= inv; v[i].z *= inv; v[i].w *= inv;
        rp[lane + (i << 6)] = v[i];
        ushort4 ov = { f2bf(v[i].x), f2bf(v[i].y), f2bf(v[i].z), f2bf(v[i].w) };
        *(ushort4*)&op[(lane + (i << 6)) * 4] = ov;
    }
}

// ---------------------------------------------------------------------------
extern "C" void kernel_launch(void* const* d_in, const int* in_sizes, int n_in,
                              void* d_out, int out_size, void* d_ws, size_t ws_size,
                              hipStream_t stream)
{
    const float* s     = (const float*)d_in[0];
    const float* h     = (const float*)d_in[1];
    const float* phi_g = (const float*)d_in[2];
    const float* phi_b = (const float*)d_in[3];
    const float* phi_m = (const float*)d_in[4];
    const float* phi_v = (const float*)d_in[5];
    const float* W_phi = (const float*)d_in[6];
    const float* psi_g = (const float*)d_in[7];
    const float* psi_b = (const float*)d_in[8];
    const float* psi_m = (const float*)d_in[9];
    const float* psi_v = (const float*)d_in[10];
    const float* W_psi = (const float*)d_in[11];
    const float* red_g = (const float*)d_in[12];
    const float* red_b = (const float*)d_in[13];
    const float* red_m = (const float*)d_in[14];
    const float* red_v = (const float*)d_in[15];
    const float* W_red = (const float*)d_in[16];

    float* out_a = (float*)d_out;                         // (H,B,Tq,Tk) f32
    float* out_c = out_a + (long)Hc * Bc * Tq * Tkc;      // (B,Tq,D)  f32

    char* p = (char*)d_ws;
    ushort* Wphi_b = (ushort*)p;  p += (long)2048 * 512 * 2;
    ushort* Wpsi_b = (ushort*)p;  p += (long)512 * 512 * 2;
    ushort* Wred_b = (ushort*)p;  p += (long)512 * 2048 * 2;
    float* bias_phi = (float*)p;  p += 2048 * 4;
    float* bias_psi = (float*)p;  p += 512 * 4;
    float* bias_red = (float*)p;  p += 512 * 4;
    ushort* s_bf  = (ushort*)p;   p += (long)8192 * 512 * 2;
    ushort* h_bf  = (ushort*)p;   p += (long)32768 * 512 * 2;
    ushort* hT_bf = (ushort*)p;   p += (long)32768 * 512 * 2;
    ushort* ms_bf = (ushort*)p;   p += (long)8192 * 2048 * 2;
    ushort* mh_bf = (ushort*)p;   p += (long)32768 * 512 * 2;
    ushort* a_bf  = ms_bf;   // alias (ms+mh dead after scores GEMM)
    ushort* ctx_bf = s_bf;   // alias (s_bf+h_bf dead after their GEMMs)

    // 1) BN folds
    fold_bn<<<2048, 256, 0, stream>>>(W_phi, phi_g, phi_b, phi_m, phi_v, Wphi_b, bias_phi, 512);
    fold_bn<<<512,  256, 0, stream>>>(W_psi, psi_g, psi_b, psi_m, psi_v, Wpsi_b, bias_psi, 512);
    fold_bn<<<512,  256, 0, stream>>>(W_red, red_g, red_b, red_m, red_v, Wred_b, bias_red, 2048);

    // 2) activation converts (+ c-output bias init for split-K atomics)
    f32_to_bf16<<<4096, 256, 0, stream>>>(s, s_bf);
    conv_h<<<dim3(8, 16, 32), 256, 0, stream>>>(h, h_bf, hT_bf);
    init_c<<<4096, 256, 0, stream>>>(out_c, bias_red);

    // 3) ms = s @ Wphi^T + bias -> bf16 (8192 x 2048, K=512), grid 32y x 8x
    gemm256<<<256, 512, 0, stream>>>(
        s_bf, Wphi_b, nullptr, ms_bf, bias_phi, 0,
        512, 512, 512, 2048, 0, 0, 0, 0, 0, 0, 1, /*nxs*/3, /*zbits*/0);

    // 4) mh = h @ Wpsi^T + bias -> bf16 (32768 x 512, K=512), grid 128y x 2x
    gemm256<<<256, 512, 0, stream>>>(
        h_bf, Wpsi_b, nullptr, mh_bf, bias_psi, 0,
        512, 512, 512, 512, 0, 0, 0, 0, 0, 0, 1, /*nxs*/1, /*zbits*/0);

    // 5) e = ms4 . mh^T -> f32 out_a (128 batches of 256x1024, K=512), 4x z128
    gemm256<<<4 * 128, 512, 0, stream>>>(
        ms_bf, mh_bf, out_a, nullptr, nullptr, 0,
        512, 2048, 512, 1024,
        /*sAh*/ 512, /*sAb*/ (long)Tq * 2048,
        /*sBh*/ 0, /*sBb*/ (long)Tkc * 512,
        /*sCh*/ (long)Bc * Tq * Tkc, /*sCb*/ (long)Tq * Tkc,
        Bc, /*nxs*/2, /*zbits*/7);

    // 6) softmax rows + bf16 copy
    softmax_rows<<<(Hc * Bc * Tq) / 4, 256, 0, stream>>>(out_a, a_bf);

    // 7) ctx = a . h (via hT, NT) -> bf16 (128 batches 256x512, K=1024), 2x z128
    gemm256<<<2 * 128, 512, 0, stream>>>(
        a_bf, hT_bf, nullptr, ctx_bf, nullptr, 0,
        1024, 1024, 1024, 2048,
        /*sAh*/ (long)Bc * Tq * Tkc, /*sAb*/ (long)Tq * Tkc,
        /*sBh*/ 0, /*sBb*/ (long)Dc * Tkc,
        /*sCh*/ 512, /*sCb*/ (long)Tq * 2048,
        Bc, /*nxs*/1, /*zbits*/7);

    // 8) c += ctx @ Wred^T (split-K x4, atomic f32; bias pre-initialized)
    //    grid 32y x 2x x 4 chunks; chunk = z: A/B advance 512 in k
    gemm256<<<32 * 2 * 4, 512, 0, stream>>>(
        ctx_bf, Wred_b, out_c, nullptr, nullptr, 1,
        512, 2048, 2048, 512,
        /*sAh*/ 512, /*sAb*/ 0,
        /*sBh*/ 512, /*sBb*/ 0,
        /*sCh*/ 0, /*sCb*/ 0,
        1, /*nxs*/1, /*zbits*/2);
}